// Round 1
// baseline (4175.507 us; speedup 1.0000x reference)
//
#include <hip/hip_runtime.h>
#include <hip/hip_bf16.h>
#include <stdint.h>

// GRU sequence decoder, fully fused.
//   B=32768, LATENT=HIDDEN=512, VOCAB=10, SEQ=6.
//   gi = x@w_ih^T (+b_ih, +b_hh for r/z gates)  -> ws (bf16), computed once
//   6x: gh = h@w_hh^T (MFMA), GRU cell (VALU), logits (1-column MFMA)
// One block = 128 batch rows, 8 waves, h tile in LDS (bf16, XOR-swizzled).
// MFMA: v_mfma_f32_16x16x32_bf16.
//   A frag: row = lane&15, k = (lane>>4)*8 + j   (8 contiguous bf16 = b128)
//   B frag: col = lane&15, k = (lane>>4)*8 + j
//   C/D   : col = lane&15, row = (lane>>4)*4 + reg   [m89-verified]

typedef __bf16 bf16_t;
typedef bf16_t bf16x8 __attribute__((ext_vector_type(8)));
typedef bf16_t bf16x4 __attribute__((ext_vector_type(4)));
typedef float  f32x4  __attribute__((ext_vector_type(4)));

#define BM      128
#define THREADS 512
#define NSTEP   6

// ws layout (bytes)
#define WIH_OFF   0u            // 1536*512*2 = 1572864
#define WHH_OFF   1572864u
#define WOPAD_OFF 3145728u      // 16*512*2 (vocab padded 10->16)
#define GI_OFF    4194304u      // 32768*1536*2 = 100663296
#define HN_OFF    104857600u    // 32768*512*2  = 33554432  (total 138412032)

__device__ __forceinline__ float sigm(float v) { return 1.0f / (1.0f + __expf(-v)); }
__device__ __forceinline__ float tanh_fast(float v) {
  v = fminf(fmaxf(v, -15.0f), 15.0f);
  float e = __expf(2.0f * v);
  return (e - 1.0f) / (e + 1.0f);
}

__global__ void prep_kernel(const float* __restrict__ wih_f, const float* __restrict__ whh_f,
                            const float* __restrict__ wout_f,
                            bf16_t* __restrict__ wih, bf16_t* __restrict__ whh,
                            bf16_t* __restrict__ wopad) {
  int i = blockIdx.x * 256 + threadIdx.x;
  if (i < 1536 * 512) {
    wih[i] = (bf16_t)wih_f[i];
    whh[i] = (bf16_t)whh_f[i];
  }
  if (i < 16 * 512) {
    int v = i >> 9, k = i & 511;
    wopad[i] = (v < 10) ? (bf16_t)wout_f[v * 512 + k] : (bf16_t)0.0f;
  }
}

__global__ __launch_bounds__(THREADS, 2) void gru_kernel(
    const float* __restrict__ x, const float* __restrict__ b_ih,
    const float* __restrict__ b_hh, const float* __restrict__ b_out,
    const char* __restrict__ wih, const char* __restrict__ whh,
    const char* __restrict__ wopad,
    bf16_t* __restrict__ gi, bf16_t* __restrict__ hnext,
    float* __restrict__ out) {
  // h tile: 128 rows x 512 bf16 = 128 KiB. Row = 1024 B.
  // Physical byte kb holds logical byte kb ^ ((row&7)<<4)  (bank-conflict swizzle).
  __shared__ __align__(16) char hlds[BM * 1024];

  const int tid   = (int)threadIdx.x;
  const int lane  = tid & 63;
  const int wq    = tid >> 6;         // wave 0..7
  const int l15   = lane & 15;
  const int lk    = lane >> 4;        // 0..3 (k-group)
  const int brow0 = (int)blockIdx.x * BM;
  const int swzA  = (l15 & 7) << 4;   // A-frag row = mt*16 + l15 -> row&7 == l15&7

  // ---------------- phase 0: x -> bf16 -> hlds (h0 = x) ----------------
  #pragma unroll
  for (int it = 0; it < 32; ++it) {
    int flat4 = it * THREADS + tid;        // 0..16383 float4s
    int row   = flat4 >> 7;                // 128 float4 per row
    int c4    = flat4 & 127;
    float4 v  = ((const float4*)(x + (size_t)(brow0 + row) * 512))[c4];
    bf16x4 h4 = { (bf16_t)v.x, (bf16_t)v.y, (bf16_t)v.z, (bf16_t)v.w };
    int kb    = (c4 * 8) ^ ((row & 7) << 4);
    *(bf16x4*)(&hlds[row * 1024 + kb]) = h4;
  }
  __syncthreads();

  const int j0w = wq * 64;   // wave owns hidden dims [wq*64, wq*64+64)

  // ---------------- phase 1: gi = x @ w_ih^T + b_ih (+ b_hh for r,z) ----------------
  for (int sw = 0; sw < 4; ++sw) {
    const int j = j0w + sw * 16 + l15;     // this lane's hidden column
    f32x4 acc[3][8];
    #pragma unroll
    for (int g = 0; g < 3; ++g)
      #pragma unroll
      for (int mt = 0; mt < 8; ++mt) acc[g][mt] = (f32x4){0.f, 0.f, 0.f, 0.f};

    const char* wb0 = wih + ((size_t)(0 * 512 + j) * 512 + lk * 8) * 2;
    const char* wb1 = wih + ((size_t)(1 * 512 + j) * 512 + lk * 8) * 2;
    const char* wb2 = wih + ((size_t)(2 * 512 + j) * 512 + lk * 8) * 2;

    #pragma unroll
    for (int kk = 0; kk < 16; ++kk) {
      int kb = ((kk * 64) | (lk * 16)) ^ swzA;
      bf16x8 a[8];
      #pragma unroll
      for (int mt = 0; mt < 8; ++mt)
        a[mt] = *(const bf16x8*)(&hlds[(mt * 16 + l15) * 1024 + kb]);
      bf16x8 br = *(const bf16x8*)(wb0 + kk * 64);
      bf16x8 bz = *(const bf16x8*)(wb1 + kk * 64);
      bf16x8 bn = *(const bf16x8*)(wb2 + kk * 64);
      #pragma unroll
      for (int mt = 0; mt < 8; ++mt) {
        acc[0][mt] = __builtin_amdgcn_mfma_f32_16x16x32_bf16(a[mt], br, acc[0][mt], 0, 0, 0);
        acc[1][mt] = __builtin_amdgcn_mfma_f32_16x16x32_bf16(a[mt], bz, acc[1][mt], 0, 0, 0);
        acc[2][mt] = __builtin_amdgcn_mfma_f32_16x16x32_bf16(a[mt], bn, acc[2][mt], 0, 0, 0);
      }
    }
    // epilogue: fold biases. b_hh_n is NOT folded (multiplied by r in the cell).
    float bir = b_ih[j] + b_hh[j];
    float biz = b_ih[512 + j] + b_hh[512 + j];
    float bin = b_ih[1024 + j];
    #pragma unroll
    for (int mt = 0; mt < 8; ++mt)
      #pragma unroll
      for (int r = 0; r < 4; ++r) {
        int row   = mt * 16 + lk * 4 + r;
        size_t go = (size_t)(brow0 + row) * 1536;
        gi[go + j]        = (bf16_t)(acc[0][mt][r] + bir);
        gi[go + 512 + j]  = (bf16_t)(acc[1][mt][r] + biz);
        gi[go + 1024 + j] = (bf16_t)(acc[2][mt][r] + bin);
      }
  }
  __syncthreads();   // drains gi stores (vmcnt) before step loop reads them

  // ---------------- phase 2: 6 recurrent steps ----------------
  for (int t = 0; t < NSTEP; ++t) {
    // gh = h @ w_hh^T ; GRU cell ; h_new -> hnext (global ws)
    for (int sw = 0; sw < 4; ++sw) {
      const int j = j0w + sw * 16 + l15;
      f32x4 acc[3][8];
      #pragma unroll
      for (int g = 0; g < 3; ++g)
        #pragma unroll
        for (int mt = 0; mt < 8; ++mt) acc[g][mt] = (f32x4){0.f, 0.f, 0.f, 0.f};

      const char* wb0 = whh + ((size_t)(0 * 512 + j) * 512 + lk * 8) * 2;
      const char* wb1 = whh + ((size_t)(1 * 512 + j) * 512 + lk * 8) * 2;
      const char* wb2 = whh + ((size_t)(2 * 512 + j) * 512 + lk * 8) * 2;

      #pragma unroll
      for (int kk = 0; kk < 16; ++kk) {
        int kb = ((kk * 64) | (lk * 16)) ^ swzA;
        bf16x8 a[8];
        #pragma unroll
        for (int mt = 0; mt < 8; ++mt)
          a[mt] = *(const bf16x8*)(&hlds[(mt * 16 + l15) * 1024 + kb]);
        bf16x8 br = *(const bf16x8*)(wb0 + kk * 64);
        bf16x8 bz = *(const bf16x8*)(wb1 + kk * 64);
        bf16x8 bn = *(const bf16x8*)(wb2 + kk * 64);
        #pragma unroll
        for (int mt = 0; mt < 8; ++mt) {
          acc[0][mt] = __builtin_amdgcn_mfma_f32_16x16x32_bf16(a[mt], br, acc[0][mt], 0, 0, 0);
          acc[1][mt] = __builtin_amdgcn_mfma_f32_16x16x32_bf16(a[mt], bz, acc[1][mt], 0, 0, 0);
          acc[2][mt] = __builtin_amdgcn_mfma_f32_16x16x32_bf16(a[mt], bn, acc[2][mt], 0, 0, 0);
        }
      }
      // cell epilogue
      float bhn = b_hh[1024 + j];
      #pragma unroll
      for (int mt = 0; mt < 8; ++mt)
        #pragma unroll
        for (int r = 0; r < 4; ++r) {
          int row   = mt * 16 + lk * 4 + r;
          size_t go = (size_t)(brow0 + row) * 1536;
          float gr = (float)gi[go + j]        + acc[0][mt][r];
          float gz = (float)gi[go + 512 + j]  + acc[1][mt][r];
          float gn = (float)gi[go + 1024 + j];
          float rv = sigm(gr);
          float zv = sigm(gz);
          float nv = tanh_fast(gn + rv * (acc[2][mt][r] + bhn));
          float hold = (float)(*(const bf16_t*)(
              &hlds[row * 1024 + ((2 * j) ^ ((row & 7) << 4))]));
          float hnew = (1.0f - zv) * nv + zv * hold;
          hnext[(size_t)(brow0 + row) * 512 + j] = (bf16_t)hnew;
        }
    }
    __syncthreads();          // all cell stores drained (vmcnt) before copy-back
    __threadfence_block();    // same-CU visibility of cross-wave global stores

    // copy-back: hnext -> hlds (pre-swizzled source, coalesced 1 KiB per wave-load)
    #pragma unroll
    for (int it2 = 0; it2 < 16; ++it2) {
      int row = wq * 16 + it2;
      int kb  = lane * 16;
      int kbs = kb ^ ((row & 7) << 4);
      bf16x8 v = *(const bf16x8*)((const char*)hnext +
                                  (size_t)(brow0 + row) * 1024 + kbs);
      *(bf16x8*)(&hlds[row * 1024 + kb]) = v;
    }
    __syncthreads();          // hlds = h_{t+1} visible to all waves

    // logits_t = h_{t+1} @ w_out^T + b_out : one 16-col MFMA per wave (Mtile = wq)
    {
      f32x4 lacc = (f32x4){0.f, 0.f, 0.f, 0.f};
      const char* wob = wopad + ((size_t)l15 * 512 + lk * 8) * 2;
      #pragma unroll
      for (int kk = 0; kk < 16; ++kk) {
        int kb   = ((kk * 64) | (lk * 16)) ^ swzA;
        bf16x8 a = *(const bf16x8*)(&hlds[(wq * 16 + l15) * 1024 + kb]);
        bf16x8 b = *(const bf16x8*)(wob + kk * 64);
        lacc = __builtin_amdgcn_mfma_f32_16x16x32_bf16(a, b, lacc, 0, 0, 0);
      }
      if (l15 < 10) {
        float bo = b_out[l15];
        #pragma unroll
        for (int r = 0; r < 4; ++r) {
          int row = wq * 16 + lk * 4 + r;
          out[(size_t)(brow0 + row) * 60 + t * 10 + l15] = lacc[r] + bo;
        }
      }
    }
  }
}

extern "C" void kernel_launch(void* const* d_in, const int* in_sizes, int n_in,
                              void* d_out, int out_size, void* d_ws, size_t ws_size,
                              hipStream_t stream) {
  const float* x     = (const float*)d_in[0];
  const float* wih_f = (const float*)d_in[1];
  const float* whh_f = (const float*)d_in[2];
  const float* b_ih  = (const float*)d_in[3];
  const float* b_hh  = (const float*)d_in[4];
  const float* wout  = (const float*)d_in[5];
  const float* b_out = (const float*)d_in[6];

  char* ws = (char*)d_ws;
  bf16_t* wih = (bf16_t*)(ws + WIH_OFF);
  bf16_t* whh = (bf16_t*)(ws + WHH_OFF);
  bf16_t* wop = (bf16_t*)(ws + WOPAD_OFF);
  bf16_t* gi  = (bf16_t*)(ws + GI_OFF);
  bf16_t* hn  = (bf16_t*)(ws + HN_OFF);

  prep_kernel<<<3072, 256, 0, stream>>>(wih_f, whh_f, wout, wih, whh, wop);
  gru_kernel<<<256, THREADS, 0, stream>>>(x, b_ih, b_hh, b_out,
                                          (const char*)wih, (const char*)whh,
                                          (const char*)wop, gi, hn, (float*)d_out);
}

// Round 2
// 803.512 us; speedup vs baseline: 5.1966x; 5.1966x over previous
//
#include <hip/hip_runtime.h>
#include <hip/hip_bf16.h>
#include <stdint.h>

// GRU sequence decoder, fused. B=32768, H=L=512, VOCAB=10, SEQ=6.
// R2 structure:
//  - MFMA operands swapped: A = weight frag (M-dim = j), B = h frag (N-dim = batch)
//    -> lane holds D[j = JT*16 + lk*4 + r][batch = BT*16 + l15]: j contiguous per lane.
//  - gi stored in ws in per-lane fragment order (bf16x4 / 8B per lane): coalesced.
//    Same wave writes & reads its own gi chunks -> no cross-wave sync needed.
//  - h lives ONLY in LDS (128 KiB, XOR-swizzled byte^=(row&7)<<4); h_new held in
//    regs across barrier, then ds_write_b64. Zero global h traffic.
//  - Weights pre-shuffled into fragment order by prep kernel: inner-loop weight
//    loads are coalesced dwordx4 streams (L2-resident, 1.5 MB).
//  - 8 waves = 2 (batch-half wm) x 4 (hidden-quarter wn); per wave: 4 N-groups of
//    {2 jtiles x 3 gates} x 4 btiles -> acc = 96 f32, h-frag reuse = 6.

typedef __bf16 bf16_t;
typedef bf16_t bf16x8 __attribute__((ext_vector_type(8)));
typedef bf16_t bf16x4 __attribute__((ext_vector_type(4)));
typedef float  f32x4  __attribute__((ext_vector_type(4)));
typedef float  f32x2  __attribute__((ext_vector_type(2)));

#define THREADS 512
#define BM      128
#define NSTEP   6

// ws layout (bytes)
#define WIH_OFF 0u            // 3*32 nt * 16 kk * 64 lane * 16B = 1572864
#define WHH_OFF 1572864u
#define WOP_OFF 3145728u      // 16 kk * 64 lane * 16B = 16384
#define GI_OFF  4194304u      // 256 blk * 49152 chunks * 8B = 100663296

static __device__ __forceinline__ float sigm(float v) { return 1.0f / (1.0f + __expf(-v)); }
static __device__ __forceinline__ float tanhf_(float v) {
  v = fminf(fmaxf(v, -12.0f), 12.0f);
  float e = __expf(2.0f * v);
  return (e - 1.0f) / (e + 1.0f);
}
static __device__ __forceinline__ f32x4 up4(bf16x4 v) {
  f32x4 o; o[0] = (float)v[0]; o[1] = (float)v[1]; o[2] = (float)v[2]; o[3] = (float)v[3];
  return o;
}
static __device__ __forceinline__ bf16x4 pk4(f32x4 v) {
  bf16x4 o; o[0] = (bf16_t)v[0]; o[1] = (bf16_t)v[1]; o[2] = (bf16_t)v[2]; o[3] = (bf16_t)v[3];
  return o;
}

// Pack weights into MFMA A-frag order:
//   chunk[(nt*16 + kk)*64 + lane] = w[nt*16 + (lane&15)][kk*32 + (lane>>4)*8 .. +8]
// (nt = gate*32 + jt enumerates 16-row tiles; row = nt*16 + l15 works because
//  (nt/32)*512 + (nt%32)*16 == nt*16.)
__global__ void prep_kernel(const float* __restrict__ wih_f, const float* __restrict__ whh_f,
                            const float* __restrict__ wout_f,
                            bf16x8* __restrict__ wihPk, bf16x8* __restrict__ whhPk,
                            bf16x8* __restrict__ wopPk) {
  int c = blockIdx.x * 256 + threadIdx.x;
  int lane = c & 63, l15 = lane & 15, lk = (lane >> 4) & 3;
  if (c < 196608) {
    int cid = (c < 98304) ? c : c - 98304;
    const float* src = (c < 98304) ? wih_f : whh_f;
    bf16x8* dst = (c < 98304) ? wihPk : whhPk;
    int kk = (cid >> 6) & 15;
    int nt = cid >> 10;
    const float* p = src + (size_t)(nt * 16 + l15) * 512 + kk * 32 + lk * 8;
    bf16x8 o;
    #pragma unroll
    for (int i = 0; i < 8; ++i) o[i] = (bf16_t)p[i];
    dst[cid] = o;
  } else if (c < 197632) {
    int cid = c - 196608;          // vocab tile: 16 kk * 64 lane
    int kk = cid >> 6;
    bf16x8 o;
    if (l15 < 10) {
      const float* p = wout_f + (size_t)l15 * 512 + kk * 32 + lk * 8;
      #pragma unroll
      for (int i = 0; i < 8; ++i) o[i] = (bf16_t)p[i];
    } else {
      #pragma unroll
      for (int i = 0; i < 8; ++i) o[i] = (bf16_t)0.0f;
    }
    wopPk[cid] = o;
  }
}

__global__ __launch_bounds__(THREADS, 2) void gru_kernel(
    const float* __restrict__ x, const float* __restrict__ b_ih,
    const float* __restrict__ b_hh, const float* __restrict__ b_out,
    const bf16x8* __restrict__ wih, const bf16x8* __restrict__ whh,
    const bf16x8* __restrict__ wop,
    bf16x4* __restrict__ gi, float* __restrict__ out) {
  // h tile: 128 rows x 512 bf16, row = 1024B. Logical byte L of row r stored at
  // physical L ^ ((r&7)<<4)  (bank-conflict swizzle; B-frag reads provably
  // balanced: 8x16B granules x 8 lanes = exactly the b128 minimum phases).
  __shared__ __align__(16) char hlds[BM * 1024];

  const int tid   = (int)threadIdx.x;
  const int lane  = tid & 63;
  const int wq    = tid >> 6;      // 0..7
  const int wm    = wq >> 2;       // batch half: btiles [wm*4, wm*4+4)
  const int wn    = wq & 3;        // hidden quarter: jtiles [wn*8, wn*8+8)
  const int l15   = lane & 15;
  const int lk    = lane >> 4;
  const int brow0 = (int)blockIdx.x * BM;
  const int swz   = (l15 & 7) << 4;

  // ---------------- phase 0: x -> bf16 -> hlds (h0 = x) ----------------
  #pragma unroll
  for (int it = 0; it < 32; ++it) {
    int f4  = it * THREADS + tid;
    int row = f4 >> 7, c4 = f4 & 127;
    float4 v = ((const float4*)(x + (size_t)(brow0 + row) * 512))[c4];
    bf16x4 h4 = { (bf16_t)v.x, (bf16_t)v.y, (bf16_t)v.z, (bf16_t)v.w };
    *(bf16x4*)(&hlds[row * 1024 + ((c4 * 8) ^ ((row & 7) << 4))]) = h4;
  }
  __syncthreads();

  const size_t gibase = (size_t)blockIdx.x * 49152;  // bf16x4 chunks per block
  // gi chunk: (((wq*8 + jt)*3 + g)*4 + bt)*64 + lane

  // ---------------- gi phase: gi = x @ w_ih^T + biases ----------------
  for (int ng = 0; ng < 4; ++ng) {
    f32x4 acc[2][3][4];
    #pragma unroll
    for (int jj = 0; jj < 2; ++jj)
      #pragma unroll
      for (int g = 0; g < 3; ++g)
        #pragma unroll
        for (int bt = 0; bt < 4; ++bt) acc[jj][g][bt] = (f32x4){0.f, 0.f, 0.f, 0.f};

    #pragma unroll 4
    for (int kk = 0; kk < 16; ++kk) {
      bf16x8 hf[4];
      #pragma unroll
      for (int bt = 0; bt < 4; ++bt)
        hf[bt] = *(const bf16x8*)(&hlds[((wm * 4 + bt) * 16 + l15) * 1024 +
                                        (((kk * 64) | (lk * 16)) ^ swz)]);
      #pragma unroll
      for (int jj = 0; jj < 2; ++jj)
        #pragma unroll
        for (int g = 0; g < 3; ++g) {
          int nt = g * 32 + wn * 8 + ng * 2 + jj;
          bf16x8 wf = wih[(nt * 16 + kk) * 64 + lane];
          #pragma unroll
          for (int bt = 0; bt < 4; ++bt)
            acc[jj][g][bt] = __builtin_amdgcn_mfma_f32_16x16x32_bf16(wf, hf[bt], acc[jj][g][bt], 0, 0, 0);
        }
    }
    #pragma unroll
    for (int jj = 0; jj < 2; ++jj) {
      int jtl = ng * 2 + jj;
      int j   = (wn * 8 + jtl) * 16 + lk * 4;
      f32x4 b0 = *(const f32x4*)(b_ih + j) + *(const f32x4*)(b_hh + j);
      f32x4 b1 = *(const f32x4*)(b_ih + 512 + j) + *(const f32x4*)(b_hh + 512 + j);
      f32x4 b2 = *(const f32x4*)(b_ih + 1024 + j);   // b_hh_n stays separate (x r)
      #pragma unroll
      for (int bt = 0; bt < 4; ++bt) {
        int cb = ((wq * 8 + jtl) * 3) * 4 + bt;
        gi[gibase + ((size_t)(cb + 0) << 6) + lane] = pk4(acc[jj][0][bt] + b0);
        gi[gibase + ((size_t)(cb + 4) << 6) + lane] = pk4(acc[jj][1][bt] + b1);
        gi[gibase + ((size_t)(cb + 8) << 6) + lane] = pk4(acc[jj][2][bt] + b2);
      }
    }
  }
  // (no barrier: hlds unchanged; gi is same-lane RAW, HW-ordered)

  // ---------------- 6 recurrent steps ----------------
  for (int t = 0; t < NSTEP; ++t) {
    bf16x4 hnew[8][4];   // [jt][bt], held across barrier #1
    for (int ng = 0; ng < 4; ++ng) {
      f32x4 acc[2][3][4];
      #pragma unroll
      for (int jj = 0; jj < 2; ++jj)
        #pragma unroll
        for (int g = 0; g < 3; ++g)
          #pragma unroll
          for (int bt = 0; bt < 4; ++bt) acc[jj][g][bt] = (f32x4){0.f, 0.f, 0.f, 0.f};

      #pragma unroll 4
      for (int kk = 0; kk < 16; ++kk) {
        bf16x8 hf[4];
        #pragma unroll
        for (int bt = 0; bt < 4; ++bt)
          hf[bt] = *(const bf16x8*)(&hlds[((wm * 4 + bt) * 16 + l15) * 1024 +
                                          (((kk * 64) | (lk * 16)) ^ swz)]);
        #pragma unroll
        for (int jj = 0; jj < 2; ++jj)
          #pragma unroll
          for (int g = 0; g < 3; ++g) {
            int nt = g * 32 + wn * 8 + ng * 2 + jj;
            bf16x8 wf = whh[(nt * 16 + kk) * 64 + lane];
            #pragma unroll
            for (int bt = 0; bt < 4; ++bt)
              acc[jj][g][bt] = __builtin_amdgcn_mfma_f32_16x16x32_bf16(wf, hf[bt], acc[jj][g][bt], 0, 0, 0);
          }
      }
      // GRU cell epilogue (all loads coalesced / vector)
      #pragma unroll
      for (int jj = 0; jj < 2; ++jj) {
        int jtl = ng * 2 + jj;
        int j   = (wn * 8 + jtl) * 16 + lk * 4;
        f32x4 bn4 = *(const f32x4*)(b_hh + 1024 + j);
        #pragma unroll
        for (int bt = 0; bt < 4; ++bt) {
          int cb = ((wq * 8 + jtl) * 3) * 4 + bt;
          f32x4 gr = up4(gi[gibase + ((size_t)(cb + 0) << 6) + lane]);
          f32x4 gz = up4(gi[gibase + ((size_t)(cb + 4) << 6) + lane]);
          f32x4 gn = up4(gi[gibase + ((size_t)(cb + 8) << 6) + lane]);
          bf16x4 ho = *(const bf16x4*)(&hlds[((wm * 4 + bt) * 16 + l15) * 1024 +
                                             ((((wn * 8 + jtl) * 32) | (lk * 8)) ^ swz)]);
          f32x4 hov = up4(ho);
          f32x4 hv;
          #pragma unroll
          for (int r = 0; r < 4; ++r) {
            float rv = sigm(gr[r] + acc[jj][0][bt][r]);
            float zv = sigm(gz[r] + acc[jj][1][bt][r]);
            float nv = tanhf_(gn[r] + rv * (acc[jj][2][bt][r] + bn4[r]));
            hv[r] = (1.0f - zv) * nv + zv * hov[r];
          }
          hnew[jtl][bt] = pk4(hv);
        }
      }
    }
    __syncthreads();   // all waves done reading h_t
    #pragma unroll
    for (int jt = 0; jt < 8; ++jt)
      #pragma unroll
      for (int bt = 0; bt < 4; ++bt)
        *(bf16x4*)(&hlds[((wm * 4 + bt) * 16 + l15) * 1024 +
                         ((((wn * 8 + jt) * 32) | (lk * 8)) ^ swz)]) = hnew[jt][bt];
    __syncthreads();   // h_{t+1} visible

    // logits_t = h_{t+1} @ w_out^T + b_out ; wave wq owns btile wq
    f32x4 lacc = (f32x4){0.f, 0.f, 0.f, 0.f};
    #pragma unroll 4
    for (int kk = 0; kk < 16; ++kk) {
      bf16x8 hf = *(const bf16x8*)(&hlds[(wq * 16 + l15) * 1024 +
                                         (((kk * 64) | (lk * 16)) ^ swz)]);
      bf16x8 wf = wop[kk * 64 + lane];
      lacc = __builtin_amdgcn_mfma_f32_16x16x32_bf16(wf, hf, lacc, 0, 0, 0);
    }
    {
      size_t ob = (size_t)(brow0 + wq * 16 + l15) * 60 + t * 10 + lk * 4;
      if (lk < 2) {
        f32x2 a = { lacc[0] + b_out[lk * 4 + 0], lacc[1] + b_out[lk * 4 + 1] };
        f32x2 b = { lacc[2] + b_out[lk * 4 + 2], lacc[3] + b_out[lk * 4 + 3] };
        *(f32x2*)(out + ob) = a;
        *(f32x2*)(out + ob + 2) = b;
      } else if (lk == 2) {
        f32x2 a = { lacc[0] + b_out[8], lacc[1] + b_out[9] };
        *(f32x2*)(out + ob) = a;
      }
    }
  }
}

extern "C" void kernel_launch(void* const* d_in, const int* in_sizes, int n_in,
                              void* d_out, int out_size, void* d_ws, size_t ws_size,
                              hipStream_t stream) {
  const float* x     = (const float*)d_in[0];
  const float* wih_f = (const float*)d_in[1];
  const float* whh_f = (const float*)d_in[2];
  const float* b_ih  = (const float*)d_in[3];
  const float* b_hh  = (const float*)d_in[4];
  const float* wout  = (const float*)d_in[5];
  const float* b_out = (const float*)d_in[6];

  char* ws = (char*)d_ws;
  bf16x8* wihPk = (bf16x8*)(ws + WIH_OFF);
  bf16x8* whhPk = (bf16x8*)(ws + WHH_OFF);
  bf16x8* wopPk = (bf16x8*)(ws + WOP_OFF);
  bf16x4* gi    = (bf16x4*)(ws + GI_OFF);

  prep_kernel<<<772, 256, 0, stream>>>(wih_f, whh_f, wout, wihPk, whhPk, wopPk);
  gru_kernel<<<256, THREADS, 0, stream>>>(x, b_ih, b_hh, b_out,
                                          wihPk, whhPk, wopPk, gi, (float*)d_out);
}